// Round 1
// baseline (350.468 us; speedup 1.0000x reference)
//
#include <hip/hip_runtime.h>

typedef unsigned short u16;
typedef unsigned int u32;
typedef __attribute__((ext_vector_type(8))) short bf16x8;   // 8 bf16 in 4 VGPRs
typedef __attribute__((ext_vector_type(4))) float f32x4;

// ---------- bf16 helpers (RNE) ----------
__device__ __forceinline__ u16 f2bf(float f) {
  union { float f; u32 u; } v; v.f = f;
  u32 u = v.u;
  return (u16)((u + 0x7FFFu + ((u >> 16) & 1u)) >> 16);
}
__device__ __forceinline__ float bf2f(u16 s) {
  union { u32 u; float f; } v; v.u = ((u32)s) << 16;
  return v.f;
}

// ---------- async global->LDS (16B per lane) ----------
__device__ __forceinline__ void async16(const void* g, void* l) {
  __builtin_amdgcn_global_load_lds(
      (__attribute__((address_space(1))) void*)g,
      (__attribute__((address_space(3))) void*)l, 16, 0, 0);
}

// ---------- elementwise cast f32 -> bf16, 4 per thread ----------
__global__ void cast4_kernel(const float* __restrict__ in, u16* __restrict__ out, int n4) {
  int i = blockIdx.x * 256 + threadIdx.x;
  if (i < n4) {
    float4 v = ((const float4*)in)[i];
    ushort4 o;
    o.x = f2bf(v.x); o.y = f2bf(v.y); o.z = f2bf(v.z); o.w = f2bf(v.w);
    ((ushort4*)out)[i] = o;
  }
}

// ---------- transpose + cast: in (R x C) f32 -> out (C x R) bf16 ----------
__global__ void transpose_cast_kernel(const float* __restrict__ in, u16* __restrict__ out,
                                      int R, int C) {
  __shared__ float tile[32][33];
  int c0 = blockIdx.x * 32, r0 = blockIdx.y * 32;
  int tx = threadIdx.x, ty = threadIdx.y;
#pragma unroll
  for (int i = ty; i < 32; i += 8) tile[i][tx] = in[(size_t)(r0 + i) * C + c0 + tx];
  __syncthreads();
#pragma unroll
  for (int i = ty; i < 32; i += 8)
    out[(size_t)(c0 + i) * R + r0 + tx] = f2bf(tile[tx][i]);
}

// ---------- cos/sin table from freqs (S x 64) ----------
__global__ void trig_kernel(const float* __restrict__ freqs, float* __restrict__ ct,
                            float* __restrict__ st, int n) {
  int i = blockIdx.x * 256 + threadIdx.x;
  if (i < n) { float f = freqs[i]; ct[i] = cosf(f); st[i] = sinf(f); }
}

// ---------- RoPE in-place on q and k (bf16, layout (S, H*HD)) ----------
__global__ void rope_kernel(u16* __restrict__ q, u16* __restrict__ k,
                            const float* __restrict__ ct, const float* __restrict__ st) {
  int i = blockIdx.x * 256 + threadIdx.x;     // over S*H*32 = 2,097,152
  int dp = (i & 31) * 2;
  int hh = (i >> 5) & 15;
  int s  = i >> 9;
  float c0 = ct[s * 64 + dp], c1 = ct[s * 64 + dp + 1];
  float s0 = st[s * 64 + dp], s1 = st[s * 64 + dp + 1];
  size_t base = (size_t)s * 2048 + hh * 128 + dp;
  {
    u32 lo = *(u32*)(q + base);
    u32 hi = *(u32*)(q + base + 64);
    float a0 = bf2f((u16)lo), a1 = bf2f((u16)(lo >> 16));
    float b0 = bf2f((u16)hi), b1 = bf2f((u16)(hi >> 16));
    u32 nlo = (u32)f2bf(a0 * c0 - b0 * s0) | ((u32)f2bf(a1 * c1 - b1 * s1) << 16);
    u32 nhi = (u32)f2bf(b0 * c0 + a0 * s0) | ((u32)f2bf(b1 * c1 + a1 * s1) << 16);
    *(u32*)(q + base) = nlo;
    *(u32*)(q + base + 64) = nhi;
  }
  {
    u32 lo = *(u32*)(k + base);
    u32 hi = *(u32*)(k + base + 64);
    float a0 = bf2f((u16)lo), a1 = bf2f((u16)(lo >> 16));
    float b0 = bf2f((u16)hi), b1 = bf2f((u16)(hi >> 16));
    u32 nlo = (u32)f2bf(a0 * c0 - b0 * s0) | ((u32)f2bf(a1 * c1 - b1 * s1) << 16);
    u32 nhi = (u32)f2bf(b0 * c0 + a0 * s0) | ((u32)f2bf(b1 * c1 + a1 * s1) << 16);
    *(u32*)(k + base) = nlo;
    *(u32*)(k + base + 64) = nhi;
  }
}

// ---------- bf16 GEMM: C(MxN) = A(MxK) * Bt(NxK)^T, f32 accumulate ----------
// 128x128 tile, BK=64, 4 waves (2x2), 4x4 16x16x32 fragments per wave.
// global_load_lds staging with read-side XOR swizzle (pre-swizzled source).
template <int OUTBF>
__launch_bounds__(256, 2)
__global__ void gemm128_kernel(const u16* __restrict__ A, const u16* __restrict__ Bt,
                               void* __restrict__ C, int M, int N, int K) {
  __shared__ __align__(16) u16 As[128 * 64];
  __shared__ __align__(16) u16 Bs[128 * 64];
  const int tid  = threadIdx.x;
  const int lane = tid & 63;
  const int wave = tid >> 6;
  const int wr = wave >> 1, wc = wave & 1;
  const int brow = blockIdx.y * 128;
  const int bcol = blockIdx.x * 128;

  int a_goff[4], b_goff[4], l_off[4];
#pragma unroll
  for (int i = 0; i < 4; ++i) {
    int p = (wave * 4 + i) * 1024 + lane * 16;        // linear byte in 16KB tile
    int row = p >> 7;                                 // 128B per row (64 bf16)
    int colb = (p & 127) ^ ((row & 7) << 4);          // inverse swizzle on source
    a_goff[i] = (brow + row) * K + (colb >> 1);
    b_goff[i] = (bcol + row) * K + (colb >> 1);
    l_off[i] = p;
  }

  f32x4 acc[4][4];
#pragma unroll
  for (int m = 0; m < 4; ++m)
#pragma unroll
    for (int n = 0; n < 4; ++n) acc[m][n] = (f32x4){0.f, 0.f, 0.f, 0.f};

  for (int k0 = 0; k0 < K; k0 += 64) {
#pragma unroll
    for (int i = 0; i < 4; ++i) {
      async16(A + a_goff[i] + k0, (char*)As + l_off[i]);
      async16(Bt + b_goff[i] + k0, (char*)Bs + l_off[i]);
    }
    __syncthreads();
#pragma unroll
    for (int kk = 0; kk < 2; ++kk) {
      bf16x8 af[4], bfr[4];
#pragma unroll
      for (int m = 0; m < 4; ++m) {
        int row = wr * 64 + m * 16 + (lane & 15);
        int byte = (row << 7) + ((kk * 64 + ((lane >> 4) << 4)) ^ ((row & 7) << 4));
        af[m] = *(const bf16x8*)((const char*)As + byte);
      }
#pragma unroll
      for (int n = 0; n < 4; ++n) {
        int row = wc * 64 + n * 16 + (lane & 15);
        int byte = (row << 7) + ((kk * 64 + ((lane >> 4) << 4)) ^ ((row & 7) << 4));
        bfr[n] = *(const bf16x8*)((const char*)Bs + byte);
      }
#pragma unroll
      for (int m = 0; m < 4; ++m)
#pragma unroll
        for (int n = 0; n < 4; ++n)
          acc[m][n] = __builtin_amdgcn_mfma_f32_16x16x32_bf16(af[m], bfr[n], acc[m][n], 0, 0, 0);
    }
    __syncthreads();
  }

  const int r0 = brow + wr * 64;
  const int c0 = bcol + wc * 64;
#pragma unroll
  for (int m = 0; m < 4; ++m)
#pragma unroll
    for (int n = 0; n < 4; ++n)
#pragma unroll
      for (int r = 0; r < 4; ++r) {
        int rr = r0 + m * 16 + ((lane >> 4) << 2) + r;
        int cc = c0 + n * 16 + (lane & 15);
        if (OUTBF) ((u16*)C)[(size_t)rr * N + cc] = f2bf(acc[m][n][r]);
        else       ((float*)C)[(size_t)rr * N + cc] = acc[m][n][r];
      }
}

// ---------- sparse tile attention: one block per (tile t, head h) ----------
// 17 key tiles (16 anchors + local), 272 keys padded to 288 with zero weights.
__launch_bounds__(256, 1)
__global__ void attn_kernel(const u16* __restrict__ Q, const u16* __restrict__ Kx,
                            const u16* __restrict__ V, const int* __restrict__ anchors,
                            u16* __restrict__ Out) {
  const int t = blockIdx.x;   // 0..255
  const int h = blockIdx.y;   // 0..15
  __shared__ int tiles[18];
  __shared__ __align__(16) u16 w_lds[16][296];   // softmax weights, q x key (288 used)
  __shared__ __align__(16) u16 vt[128][296];     // V^T: [d][key]
  __shared__ float lg[16][292];                  // raw logits, q x key
  const int tid  = threadIdx.x;
  const int lane = tid & 63;
  const int wave = tid >> 6;

  if (tid < 16) tiles[tid] = anchors[(size_t)((h << 12) + (t * 16 + 15)) * 16 + tid];
  if (tid == 16) tiles[16] = t;      // local tile (order: anchors then local)
  if (tid == 17) tiles[17] = 0;      // pad tile (zero weights later)
  __syncthreads();

  // stage V^T into LDS: wave w covers keys [w*72, w*72+72)
  {
    const int key0 = wave * 72;
    for (int key = key0; key < key0 + 72; ++key) {
      int token = tiles[key >> 4] * 16 + (key & 15);
      token = min(token, 4095);
      u32 v32 = *(const u32*)(V + (size_t)token * 2048 + h * 128 + 2 * lane);
      vt[2 * lane][key]     = (u16)(v32 & 0xffffu);
      vt[2 * lane + 1][key] = (u16)(v32 >> 16);
    }
  }

  // logits: Q(16x128) . K_tile(16x128)^T per key tile, tiles split across waves
  {
    const u16* qbase = Q + (size_t)(t * 16 + (lane & 15)) * 2048 + h * 128 + ((lane >> 4) << 3);
    bf16x8 qf[4];
#pragma unroll
    for (int ks = 0; ks < 4; ++ks) qf[ks] = *(const bf16x8*)(qbase + ks * 32);
    for (int j = wave; j < 17; j += 4) {
      int tok = tiles[j] * 16 + (lane & 15);
      tok = min(tok, 4095);
      const u16* kbase = Kx + (size_t)tok * 2048 + h * 128 + ((lane >> 4) << 3);
      f32x4 a = (f32x4){0.f, 0.f, 0.f, 0.f};
#pragma unroll
      for (int ks = 0; ks < 4; ++ks) {
        bf16x8 kf = *(const bf16x8*)(kbase + ks * 32);
        a = __builtin_amdgcn_mfma_f32_16x16x32_bf16(qf[ks], kf, a, 0, 0, 0);
      }
#pragma unroll
      for (int r = 0; r < 4; ++r) {
        int qrow = ((lane >> 4) << 2) + r;
        float vv = a[r] * 0.088388347648318447f;   // 1/sqrt(128)
        if (tok > t * 16 + qrow) vv = -1e10f;      // future mask on clipped token
        lg[qrow][j * 16 + (lane & 15)] = vv;
      }
    }
  }
  __syncthreads();

  // softmax per q row: row r handled by 16 threads (c = tid&15)
  {
    const int r = tid >> 4, c = tid & 15;
    float vals[17];
    float mx = -3.0e38f;
#pragma unroll
    for (int i = 0; i < 17; ++i) { vals[i] = lg[r][i * 16 + c]; mx = fmaxf(mx, vals[i]); }
#pragma unroll
    for (int d = 1; d < 16; d <<= 1) mx = fmaxf(mx, __shfl_xor(mx, d, 64));
    float sum = 0.f;
#pragma unroll
    for (int i = 0; i < 17; ++i) { vals[i] = __expf(vals[i] - mx); sum += vals[i]; }
#pragma unroll
    for (int d = 1; d < 16; d <<= 1) sum += __shfl_xor(sum, d, 64);
    float inv = sum > 0.f ? 1.0f / sum : 0.f;
#pragma unroll
    for (int i = 0; i < 17; ++i) w_lds[r][i * 16 + c] = f2bf(vals[i] * inv);
    w_lds[r][272 + c] = 0;                         // zero the pad tile's weights
  }
  __syncthreads();

  // PV: out(16x128) = W(16x288) . V(288x128); wave handles 32 output dims
  {
    f32x4 o0 = (f32x4){0.f, 0.f, 0.f, 0.f}, o1 = o0;
    const int nf0 = wave * 2;
#pragma unroll
    for (int ks = 0; ks < 9; ++ks) {
      bf16x8 af = *(const bf16x8*)(&w_lds[lane & 15][ks * 32 + ((lane >> 4) << 3)]);
      bf16x8 b0 = *(const bf16x8*)(&vt[nf0 * 16      + (lane & 15)][ks * 32 + ((lane >> 4) << 3)]);
      bf16x8 b1 = *(const bf16x8*)(&vt[nf0 * 16 + 16 + (lane & 15)][ks * 32 + ((lane >> 4) << 3)]);
      o0 = __builtin_amdgcn_mfma_f32_16x16x32_bf16(af, b0, o0, 0, 0, 0);
      o1 = __builtin_amdgcn_mfma_f32_16x16x32_bf16(af, b1, o1, 0, 0, 0);
    }
#pragma unroll
    for (int r = 0; r < 4; ++r) {
      int qrow = ((lane >> 4) << 2) + r;
      size_t base = (size_t)(t * 16 + qrow) * 2048 + h * 128;
      Out[base + nf0 * 16 + (lane & 15)]      = f2bf(o0[r]);
      Out[base + nf0 * 16 + 16 + (lane & 15)] = f2bf(o1[r]);
    }
  }
}

extern "C" void kernel_launch(void* const* d_in, const int* in_sizes, int n_in,
                              void* d_out, int out_size, void* d_ws, size_t ws_size,
                              hipStream_t stream) {
  (void)in_sizes; (void)n_in; (void)out_size; (void)ws_size;
  const float* x      = (const float*)d_in[0];
  const float* Wq     = (const float*)d_in[1];
  const float* Wk     = (const float*)d_in[2];
  const float* Wv     = (const float*)d_in[3];
  const float* Wo     = (const float*)d_in[4];
  const float* freqs  = (const float*)d_in[5];
  const int* anchors  = (const int*)d_in[6];
  float* out = (float*)d_out;

  char* ws = (char*)d_ws;
  const size_t MB = 1024 * 1024;
  u16* xbf   = (u16*)(ws + 0);        // 16MB, reused as attn output later
  u16* wqT   = (u16*)(ws + 16 * MB);  // 8MB each (N x K bf16)
  u16* wkT   = (u16*)(ws + 24 * MB);
  u16* wvT   = (u16*)(ws + 32 * MB);
  u16* woT   = (u16*)(ws + 40 * MB);
  u16* qbf   = (u16*)(ws + 48 * MB);  // 16MB each, (S, H*HD) bf16
  u16* kbf   = (u16*)(ws + 64 * MB);
  u16* vbf   = (u16*)(ws + 80 * MB);
  u16* attnb = (u16*)(ws + 0);        // aliases xbf (x dead after projections)
  float* ct  = (float*)(ws + 96 * MB);
  float* st  = (float*)(ws + 97 * MB);

  cast4_kernel<<<8192, 256, 0, stream>>>(x, xbf, 2097152);
  dim3 tb(32, 8), tg(64, 64);
  transpose_cast_kernel<<<tg, tb, 0, stream>>>(Wq, wqT, 2048, 2048);
  transpose_cast_kernel<<<tg, tb, 0, stream>>>(Wk, wkT, 2048, 2048);
  transpose_cast_kernel<<<tg, tb, 0, stream>>>(Wv, wvT, 2048, 2048);
  transpose_cast_kernel<<<tg, tb, 0, stream>>>(Wo, woT, 2048, 2048);
  trig_kernel<<<1024, 256, 0, stream>>>(freqs, ct, st, 262144);

  dim3 gg(16, 32);   // N/128, M/128
  gemm128_kernel<1><<<gg, 256, 0, stream>>>(xbf, wqT, qbf, 4096, 2048, 2048);
  gemm128_kernel<1><<<gg, 256, 0, stream>>>(xbf, wkT, kbf, 4096, 2048, 2048);
  gemm128_kernel<1><<<gg, 256, 0, stream>>>(xbf, wvT, vbf, 4096, 2048, 2048);
  rope_kernel<<<8192, 256, 0, stream>>>(qbf, kbf, ct, st);
  attn_kernel<<<dim3(256, 16), 256, 0, stream>>>(qbf, kbf, vbf, anchors, attnb);
  gemm128_kernel<0><<<gg, 256, 0, stream>>>(attnb, woT, out, 4096, 2048, 2048);
}

// Round 2
// 280.724 us; speedup vs baseline: 1.2484x; 1.2484x over previous
//
#include <hip/hip_runtime.h>

typedef unsigned short u16;
typedef unsigned int u32;
typedef __attribute__((ext_vector_type(8))) short bf16x8;   // 8 bf16 in 4 VGPRs
typedef __attribute__((ext_vector_type(4))) float f32x4;

// ---------- bf16 helpers (RNE) ----------
__device__ __forceinline__ u16 f2bf(float f) {
  union { float f; u32 u; } v; v.f = f;
  u32 u = v.u;
  return (u16)((u + 0x7FFFu + ((u >> 16) & 1u)) >> 16);
}
__device__ __forceinline__ float bf2f(u16 s) {
  union { u32 u; float f; } v; v.u = ((u32)s) << 16;
  return v.f;
}

// ---------- async global->LDS (16B per lane) ----------
__device__ __forceinline__ void async16(const void* g, void* l) {
  __builtin_amdgcn_global_load_lds(
      (__attribute__((address_space(1))) void*)g,
      (__attribute__((address_space(3))) void*)l, 16, 0, 0);
}

// ---------- elementwise cast f32 -> bf16, 4 per thread ----------
__global__ void cast4_kernel(const float* __restrict__ in, u16* __restrict__ out, int n4) {
  int i = blockIdx.x * 256 + threadIdx.x;
  if (i < n4) {
    float4 v = ((const float4*)in)[i];
    ushort4 o;
    o.x = f2bf(v.x); o.y = f2bf(v.y); o.z = f2bf(v.z); o.w = f2bf(v.w);
    ((ushort4*)out)[i] = o;
  }
}

// ---------- transpose + cast: in (R x C) f32 -> out (C x R) bf16 ----------
__global__ void transpose_cast_kernel(const float* __restrict__ in, u16* __restrict__ out,
                                      int R, int C) {
  __shared__ float tile[32][33];
  int c0 = blockIdx.x * 32, r0 = blockIdx.y * 32;
  int tx = threadIdx.x, ty = threadIdx.y;
#pragma unroll
  for (int i = ty; i < 32; i += 8) tile[i][tx] = in[(size_t)(r0 + i) * C + c0 + tx];
  __syncthreads();
#pragma unroll
  for (int i = ty; i < 32; i += 8)
    out[(size_t)(c0 + i) * R + r0 + tx] = f2bf(tile[tx][i]);
}

// ---------- cos/sin table from freqs (S x 64) ----------
__global__ void trig_kernel(const float* __restrict__ freqs, float* __restrict__ ct,
                            float* __restrict__ st, int n) {
  int i = blockIdx.x * 256 + threadIdx.x;
  if (i < n) { float f = freqs[i]; ct[i] = cosf(f); st[i] = sinf(f); }
}

// ---------- RoPE in-place on q and k (bf16, layout (S, H*HD)) ----------
__global__ void rope_kernel(u16* __restrict__ q, u16* __restrict__ k,
                            const float* __restrict__ ct, const float* __restrict__ st) {
  int i = blockIdx.x * 256 + threadIdx.x;     // over S*H*32 = 2,097,152
  int dp = (i & 31) * 2;
  int hh = (i >> 5) & 15;
  int s  = i >> 9;
  float c0 = ct[s * 64 + dp], c1 = ct[s * 64 + dp + 1];
  float s0 = st[s * 64 + dp], s1 = st[s * 64 + dp + 1];
  size_t base = (size_t)s * 2048 + hh * 128 + dp;
  {
    u32 lo = *(u32*)(q + base);
    u32 hi = *(u32*)(q + base + 64);
    float a0 = bf2f((u16)lo), a1 = bf2f((u16)(lo >> 16));
    float b0 = bf2f((u16)hi), b1 = bf2f((u16)(hi >> 16));
    u32 nlo = (u32)f2bf(a0 * c0 - b0 * s0) | ((u32)f2bf(a1 * c1 - b1 * s1) << 16);
    u32 nhi = (u32)f2bf(b0 * c0 + a0 * s0) | ((u32)f2bf(b1 * c1 + a1 * s1) << 16);
    *(u32*)(q + base) = nlo;
    *(u32*)(q + base + 64) = nhi;
  }
  {
    u32 lo = *(u32*)(k + base);
    u32 hi = *(u32*)(k + base + 64);
    float a0 = bf2f((u16)lo), a1 = bf2f((u16)(lo >> 16));
    float b0 = bf2f((u16)hi), b1 = bf2f((u16)(hi >> 16));
    u32 nlo = (u32)f2bf(a0 * c0 - b0 * s0) | ((u32)f2bf(a1 * c1 - b1 * s1) << 16);
    u32 nhi = (u32)f2bf(b0 * c0 + a0 * s0) | ((u32)f2bf(b1 * c1 + a1 * s1) << 16);
    *(u32*)(k + base) = nlo;
    *(u32*)(k + base + 64) = nhi;
  }
}

// ---------- K repack: kbf (S, H*HD) -> Kp [h][s][128] ----------
__global__ void repack_k_kernel(const u16* __restrict__ Kin, u16* __restrict__ Kp) {
  const int h = blockIdx.y;
  const int s0 = blockIdx.x * 64;
  const int tid = threadIdx.x;
#pragma unroll
  for (int i = 0; i < 16; ++i) {
    int idx = i * 256 + tid;           // 0..4095
    int r = idx >> 6;                  // token row 0..63
    int d2 = idx & 63;                 // u32 column (2 bf16)
    u32 kv = ((const u32*)Kin)[(size_t)(s0 + r) * 1024 + h * 64 + d2];
    ((u32*)Kp)[((size_t)h * 4096 + s0 + r) * 64 + d2] = kv;
  }
}

// ---------- V repack: vbf (S, H*HD) -> VT2 [h][tile][d 0..127][key 0..15] ----------
__global__ void repack_v_kernel(const u16* __restrict__ Vin, u16* __restrict__ VT2) {
  const int h = blockIdx.y;
  const int s0 = blockIdx.x * 64;      // 4 tiles per block
  const int tid = threadIdx.x;
  __shared__ u16 lv[64][132];          // 64 tokens x 128 dims (+4 pad)
#pragma unroll
  for (int i = 0; i < 16; ++i) {
    int idx = i * 256 + tid;
    int r = idx >> 6;
    int d2 = idx & 63;
    u32 vv = ((const u32*)Vin)[(size_t)(s0 + r) * 1024 + h * 64 + d2];
    *(u32*)(&lv[r][d2 * 2]) = vv;
  }
  __syncthreads();
#pragma unroll
  for (int i = 0; i < 16; ++i) {
    int idx = i * 256 + tid;           // 0..4095
    int k2 = idx & 7;                  // u32 over 2 keys
    int d  = (idx >> 3) & 127;
    int tl = idx >> 10;                // local tile 0..3
    u32 lo = lv[tl * 16 + k2 * 2][d];
    u32 hi = lv[tl * 16 + k2 * 2 + 1][d];
    ((u32*)VT2)[(((size_t)h * 256 + blockIdx.x * 4 + tl) * 128 + d) * 8 + k2] = lo | (hi << 16);
  }
}

// ---------- bf16 GEMM: C(MxN) = A(MxK) * Bt(NxK)^T, f32 accumulate ----------
template <int OUTBF>
__launch_bounds__(256, 2)
__global__ void gemm128_kernel(const u16* __restrict__ A, const u16* __restrict__ Bt,
                               void* __restrict__ C, int M, int N, int K) {
  __shared__ __align__(16) u16 As[128 * 64];
  __shared__ __align__(16) u16 Bs[128 * 64];
  const int tid  = threadIdx.x;
  const int lane = tid & 63;
  const int wave = tid >> 6;
  const int wr = wave >> 1, wc = wave & 1;
  const int brow = blockIdx.y * 128;
  const int bcol = blockIdx.x * 128;

  int a_goff[4], b_goff[4], l_off[4];
#pragma unroll
  for (int i = 0; i < 4; ++i) {
    int p = (wave * 4 + i) * 1024 + lane * 16;        // linear byte in 16KB tile
    int row = p >> 7;                                 // 128B per row (64 bf16)
    int colb = (p & 127) ^ ((row & 7) << 4);          // inverse swizzle on source
    a_goff[i] = (brow + row) * K + (colb >> 1);
    b_goff[i] = (bcol + row) * K + (colb >> 1);
    l_off[i] = p;
  }

  f32x4 acc[4][4];
#pragma unroll
  for (int m = 0; m < 4; ++m)
#pragma unroll
    for (int n = 0; n < 4; ++n) acc[m][n] = (f32x4){0.f, 0.f, 0.f, 0.f};

  for (int k0 = 0; k0 < K; k0 += 64) {
#pragma unroll
    for (int i = 0; i < 4; ++i) {
      async16(A + a_goff[i] + k0, (char*)As + l_off[i]);
      async16(Bt + b_goff[i] + k0, (char*)Bs + l_off[i]);
    }
    __syncthreads();
#pragma unroll
    for (int kk = 0; kk < 2; ++kk) {
      bf16x8 af[4], bfr[4];
#pragma unroll
      for (int m = 0; m < 4; ++m) {
        int row = wr * 64 + m * 16 + (lane & 15);
        int byte = (row << 7) + ((kk * 64 + ((lane >> 4) << 4)) ^ ((row & 7) << 4));
        af[m] = *(const bf16x8*)((const char*)As + byte);
      }
#pragma unroll
      for (int n = 0; n < 4; ++n) {
        int row = wc * 64 + n * 16 + (lane & 15);
        int byte = (row << 7) + ((kk * 64 + ((lane >> 4) << 4)) ^ ((row & 7) << 4));
        bfr[n] = *(const bf16x8*)((const char*)Bs + byte);
      }
#pragma unroll
      for (int m = 0; m < 4; ++m)
#pragma unroll
        for (int n = 0; n < 4; ++n)
          acc[m][n] = __builtin_amdgcn_mfma_f32_16x16x32_bf16(af[m], bfr[n], acc[m][n], 0, 0, 0);
    }
    __syncthreads();
  }

  const int r0 = brow + wr * 64;
  const int c0 = bcol + wc * 64;
#pragma unroll
  for (int m = 0; m < 4; ++m)
#pragma unroll
    for (int n = 0; n < 4; ++n)
#pragma unroll
      for (int r = 0; r < 4; ++r) {
        int rr = r0 + m * 16 + ((lane >> 4) << 2) + r;
        int cc = c0 + n * 16 + (lane & 15);
        if (OUTBF) ((u16*)C)[(size_t)rr * N + cc] = f2bf(acc[m][n][r]);
        else       ((float*)C)[(size_t)rr * N + cc] = acc[m][n][r];
      }
}

// ---------- sparse tile attention: one block per (tile t, head h) ----------
// 17 key tiles (16 anchors + local), 272 keys padded to 288 with zero weights.
// K from Kp [h][s][128] (contiguous 4KB per tile); V from VT2 [h][tile][d][16]
// (each PV B-fragment = one aligned 16B global load). No V transpose in LDS.
__launch_bounds__(256, 3)
__global__ void attn_kernel(const u16* __restrict__ Q, const u16* __restrict__ Kp,
                            const u16* __restrict__ VT2, const int* __restrict__ anchors,
                            u16* __restrict__ Out) {
  const int t = blockIdx.x;   // 0..255
  const int h = blockIdx.y;   // 0..15
  __shared__ int tiles[18];
  __shared__ float lg[16][292];                  // raw logits, q x key
  __shared__ __align__(16) u16 w_lds[16][296];   // softmax weights, q x key (288 used)
  const int tid  = threadIdx.x;
  const int lane = tid & 63;
  const int wave = tid >> 6;
  const int g = lane >> 4;          // k-group 0..3
  const int c = lane & 15;

  if (tid < 16) tiles[tid] = anchors[(size_t)((h << 12) + (t * 16 + 15)) * 16 + tid];
  if (tid == 16) tiles[16] = t;      // local tile (order: anchors then local)
  if (tid == 17) tiles[17] = 0;      // pad tile (zero weights later)
  __syncthreads();

  // logits: Q(16x128) . K_tile(16x128)^T per key tile, tiles split across waves
  {
    const u16* qbase = Q + (size_t)(t * 16 + c) * 2048 + h * 128 + g * 8;
    bf16x8 qf[4];
#pragma unroll
    for (int ks = 0; ks < 4; ++ks) qf[ks] = *(const bf16x8*)(qbase + ks * 32);
    for (int j = wave; j < 17; j += 4) {
      int tok = tiles[j] * 16 + c;
      const u16* kbase = Kp + ((size_t)h * 4096 + tok) * 128 + g * 8;
      f32x4 a = (f32x4){0.f, 0.f, 0.f, 0.f};
#pragma unroll
      for (int ks = 0; ks < 4; ++ks) {
        bf16x8 kf = *(const bf16x8*)(kbase + ks * 32);
        a = __builtin_amdgcn_mfma_f32_16x16x32_bf16(qf[ks], kf, a, 0, 0, 0);
      }
#pragma unroll
      for (int r = 0; r < 4; ++r) {
        int qrow = g * 4 + r;
        float vv = a[r] * 0.088388347648318447f;   // 1/sqrt(128)
        if (tok > t * 16 + qrow) vv = -1e10f;      // future mask
        lg[qrow][j * 16 + c] = vv;
      }
    }
  }
  __syncthreads();

  // softmax per q row: row r handled by 16 threads (col = tid&15)
  {
    const int r = tid >> 4, cc = tid & 15;
    float vals[17];
    float mx = -3.0e38f;
#pragma unroll
    for (int i = 0; i < 17; ++i) { vals[i] = lg[r][i * 16 + cc]; mx = fmaxf(mx, vals[i]); }
#pragma unroll
    for (int d = 1; d < 16; d <<= 1) mx = fmaxf(mx, __shfl_xor(mx, d, 64));
    float sum = 0.f;
#pragma unroll
    for (int i = 0; i < 17; ++i) { vals[i] = __expf(vals[i] - mx); sum += vals[i]; }
#pragma unroll
    for (int d = 1; d < 16; d <<= 1) sum += __shfl_xor(sum, d, 64);
    float inv = sum > 0.f ? 1.0f / sum : 0.f;
#pragma unroll
    for (int i = 0; i < 17; ++i) w_lds[r][i * 16 + cc] = f2bf(vals[i] * inv);
    w_lds[r][272 + cc] = 0;                        // zero the pad tile's weights
  }
  __syncthreads();

  // PV: out(16x288 . 288x128); wave owns 32 output dims; B direct from VT2
  {
    f32x4 o0 = (f32x4){0.f, 0.f, 0.f, 0.f}, o1 = o0;
    const int d0 = wave * 32;
    const size_t hb = (size_t)h * 256;
    const int keyin = (g & 1) * 8;
#pragma unroll
    for (int ks = 0; ks < 9; ++ks) {
      bf16x8 af = *(const bf16x8*)(&w_lds[c][ks * 32 + g * 8]);
      int jt = 2 * ks + (g >> 1);
      const u16* vb = VT2 + (hb + tiles[jt]) * 128 * 16;
      bf16x8 b0 = *(const bf16x8*)(vb + (d0 + c) * 16 + keyin);
      bf16x8 b1 = *(const bf16x8*)(vb + (d0 + 16 + c) * 16 + keyin);
      o0 = __builtin_amdgcn_mfma_f32_16x16x32_bf16(af, b0, o0, 0, 0, 0);
      o1 = __builtin_amdgcn_mfma_f32_16x16x32_bf16(af, b1, o1, 0, 0, 0);
    }
#pragma unroll
    for (int r = 0; r < 4; ++r) {
      int qrow = g * 4 + r;
      size_t base = (size_t)(t * 16 + qrow) * 2048 + h * 128;
      Out[base + d0 + c]      = f2bf(o0[r]);
      Out[base + d0 + 16 + c] = f2bf(o1[r]);
    }
  }
}

extern "C" void kernel_launch(void* const* d_in, const int* in_sizes, int n_in,
                              void* d_out, int out_size, void* d_ws, size_t ws_size,
                              hipStream_t stream) {
  (void)in_sizes; (void)n_in; (void)out_size; (void)ws_size;
  const float* x      = (const float*)d_in[0];
  const float* Wq     = (const float*)d_in[1];
  const float* Wk     = (const float*)d_in[2];
  const float* Wv     = (const float*)d_in[3];
  const float* Wo     = (const float*)d_in[4];
  const float* Wo_f   = (const float*)d_in[4];
  const float* freqs  = (const float*)d_in[5];
  const int* anchors  = (const int*)d_in[6];
  (void)Wo_f;
  float* out = (float*)d_out;

  char* ws = (char*)d_ws;
  const size_t MB = 1024 * 1024;
  // Layout (96 MB total, aliasing dead buffers):
  //  0..16  : xbf, later attnb (x dead after projections)
  // 16..32  : wqT(16..24), wkT(24..32); later Kp (both dead after q,k GEMMs)
  // 32..40  : wvT; later ct(32..33), st(33..34) (wvT dead after v GEMM)
  // 40..48  : woT (live until final GEMM)
  // 48..64  : qbf
  // 64..80  : kbf; later VT2 (kbf dead after repack_k)
  // 80..96  : vbf
  u16* xbf   = (u16*)(ws + 0);
  u16* wqT   = (u16*)(ws + 16 * MB);
  u16* wkT   = (u16*)(ws + 24 * MB);
  u16* wvT   = (u16*)(ws + 32 * MB);
  u16* woT   = (u16*)(ws + 40 * MB);
  u16* qbf   = (u16*)(ws + 48 * MB);
  u16* kbf   = (u16*)(ws + 64 * MB);
  u16* vbf   = (u16*)(ws + 80 * MB);
  u16* attnb = (u16*)(ws + 0);
  u16* Kp    = (u16*)(ws + 16 * MB);
  float* ct  = (float*)(ws + 32 * MB);
  float* st  = (float*)(ws + 33 * MB);
  u16* VT2   = (u16*)(ws + 64 * MB);

  cast4_kernel<<<8192, 256, 0, stream>>>(x, xbf, 2097152);
  dim3 tb(32, 8), tg(64, 64);
  transpose_cast_kernel<<<tg, tb, 0, stream>>>(Wq, wqT, 2048, 2048);
  transpose_cast_kernel<<<tg, tb, 0, stream>>>(Wk, wkT, 2048, 2048);
  transpose_cast_kernel<<<tg, tb, 0, stream>>>(Wv, wvT, 2048, 2048);
  transpose_cast_kernel<<<tg, tb, 0, stream>>>(Wo, woT, 2048, 2048);

  dim3 gg(16, 32);   // N/128, M/128
  gemm128_kernel<1><<<gg, 256, 0, stream>>>(xbf, wqT, qbf, 4096, 2048, 2048);
  gemm128_kernel<1><<<gg, 256, 0, stream>>>(xbf, wkT, kbf, 4096, 2048, 2048);
  gemm128_kernel<1><<<gg, 256, 0, stream>>>(xbf, wvT, vbf, 4096, 2048, 2048);
  trig_kernel<<<1024, 256, 0, stream>>>(freqs, ct, st, 262144);   // over dead wvT
  rope_kernel<<<8192, 256, 0, stream>>>(qbf, kbf, ct, st);
  repack_k_kernel<<<dim3(64, 16), 256, 0, stream>>>(kbf, Kp);     // over dead wqT/wkT
  repack_v_kernel<<<dim3(64, 16), 256, 0, stream>>>(vbf, VT2);    // over dead kbf
  attn_kernel<<<dim3(256, 16), 256, 0, stream>>>(qbf, Kp, VT2, anchors, attnb);
  gemm128_kernel<0><<<gg, 256, 0, stream>>>(attnb, woT, out, 4096, 2048, 2048);
}